// Round 1
// baseline (654.124 us; speedup 1.0000x reference)
//
#include <hip/hip_runtime.h>

#define BB 1024
#define TT 256
#define EE 384
#define HH 64

typedef float  f32x4  __attribute__((ext_vector_type(4)));
typedef float  f32x4v __attribute__((ext_vector_type(4)));
typedef short  short8 __attribute__((ext_vector_type(8)));
typedef unsigned short us4 __attribute__((ext_vector_type(4)));

// fp32 -> bf16 round-to-nearest-even
__device__ __forceinline__ unsigned short f2bf(float f) {
    unsigned int u = __float_as_uint(f);
    u += 0x7FFFu + ((u >> 16) & 1u);
    return (unsigned short)(u >> 16);
}

// Build Wt[n][k] bf16, n in [0,192): columns of Wq (pre-scaled by 1/8*log2e) | Wk | Wv.
// Transposed so MFMA B-fragment reads (8 contiguous k) are 16B loads.
__global__ void prep_kernel(const float* __restrict__ Wq, const float* __restrict__ Wk,
                            const float* __restrict__ Wv, unsigned short* __restrict__ Wt) {
    int i = blockIdx.x * 256 + threadIdx.x;   // 192*384 = 73728 = 288*256
    if (i >= 192 * EE) return;
    int n = i / EE, k = i - n * EE;
    float v;
    if (n < 64)       v = Wq[k * HH + n] * 0.18033688011112042f;  // 0.125 * log2(e)
    else if (n < 128) v = Wk[k * HH + (n - 64)];
    else              v = Wv[k * HH + (n - 128)];
    Wt[i] = f2bf(v);
}

// One block per batch. 512 threads = 8 waves.
// Phase 1: QKV = x @ Wt (bf16 MFMA, A from global, B from L2-cached Wt) -> LDS.
// Phase 2: flash attention from LDS, online softmax in exp2 domain.
__global__ __launch_bounds__(512, 2) void attn_kernel(const float* __restrict__ x,
                                                      const unsigned short* __restrict__ Wt,
                                                      float* __restrict__ out) {
    // padded strides: 72 (=64+8) and 264 (=256+8) keep bank aliasing at free 2-way
    __shared__ unsigned short Qs[TT * 72];    // 36864 B  Q[t][h], bf16, q pre-scaled
    __shared__ unsigned short Ks[TT * 72];    // 36864 B  K[t][h]
    __shared__ unsigned short Vt[HH * 264];   // 33792 B  V^T[h][t]
    __shared__ unsigned short Ps[8 * 1152];   // 18432 B  per-wave P scratch 16x64 (stride 72)

    const int tid  = threadIdx.x;
    const int lane = tid & 63;
    const int w    = tid >> 6;        // wave 0..7
    const int g    = lane >> 4;       // k-group / row-quad 0..3
    const int mr   = lane & 15;       // m (A) / n (B) / col (C)
    const int b    = blockIdx.x;
    const float* xb = x + (size_t)b * (TT * EE);

    // ---------------- phase 1: QKV projection ----------------
    // wave w owns M-tiles 2w and 2w+1 (rows 32w..32w+31); N = 192 (12 tiles); K = 384 (12 steps)
    f32x4 acc[2][12];
#pragma unroll
    for (int ti = 0; ti < 2; ++ti)
#pragma unroll
        for (int nt = 0; nt < 12; ++nt)
            acc[ti][nt] = (f32x4){0.f, 0.f, 0.f, 0.f};

    const int M0a = (2 * w) * 16;
    const int M0b = (2 * w + 1) * 16;

    for (int kt = 0; kt < 12; ++kt) {
        const int k0 = kt * 32 + g * 8;
        // B fragments from global (L2-resident Wt)
        short8 bfr[12];
#pragma unroll
        for (int nt = 0; nt < 12; ++nt)
            bfr[nt] = *(const short8*)(Wt + (size_t)(nt * 16 + mr) * EE + k0);
        // A fragments from global x (16 rows x 128B contiguous per wave -> cacheline-perfect)
        short8 afr[2];
#pragma unroll
        for (int ti = 0; ti < 2; ++ti) {
            const int m0 = ti ? M0b : M0a;
            const float* ap = xb + (size_t)(m0 + mr) * EE + k0;
            f32x4v lo = *(const f32x4v*)ap;
            f32x4v hi = *(const f32x4v*)(ap + 4);
            union { short8 v; unsigned short u[8]; } cv;
            cv.u[0] = f2bf(lo.x); cv.u[1] = f2bf(lo.y); cv.u[2] = f2bf(lo.z); cv.u[3] = f2bf(lo.w);
            cv.u[4] = f2bf(hi.x); cv.u[5] = f2bf(hi.y); cv.u[6] = f2bf(hi.z); cv.u[7] = f2bf(hi.w);
            afr[ti] = cv.v;
        }
#pragma unroll
        for (int nt = 0; nt < 12; ++nt) {
            acc[0][nt] = __builtin_amdgcn_mfma_f32_16x16x32_bf16(afr[0], bfr[nt], acc[0][nt], 0, 0, 0);
            acc[1][nt] = __builtin_amdgcn_mfma_f32_16x16x32_bf16(afr[1], bfr[nt], acc[1][nt], 0, 0, 0);
        }
    }

    // epilogue: C/D layout col=mr, row=g*4+reg  ->  LDS bf16
#pragma unroll
    for (int ti = 0; ti < 2; ++ti) {
        const int row = (ti ? M0b : M0a) + g * 4;
#pragma unroll
        for (int nt = 0; nt < 12; ++nt) {
            f32x4 v = acc[ti][nt];
            if (nt < 4) {
                const int col = nt * 16 + mr;
#pragma unroll
                for (int r = 0; r < 4; ++r) Qs[(row + r) * 72 + col] = f2bf(v[r]);
            } else if (nt < 8) {
                const int col = (nt - 4) * 16 + mr;
#pragma unroll
                for (int r = 0; r < 4; ++r) Ks[(row + r) * 72 + col] = f2bf(v[r]);
            } else {
                const int h = (nt - 8) * 16 + mr;   // 4 consecutive t at one h -> packed 8B store
                us4 pk;
                pk.x = f2bf(v[0]); pk.y = f2bf(v[1]); pk.z = f2bf(v[2]); pk.w = f2bf(v[3]);
                *(us4*)(&Vt[h * 264 + row]) = pk;
            }
        }
    }
    __syncthreads();

    // ---------------- phase 2: causal flash attention ----------------
    // wave w handles Q-tiles a=w and a=15-w: total key-chunks = 5 per wave (balanced)
#pragma unroll
    for (int pass = 0; pass < 2; ++pass) {
        const int a  = pass ? (15 - w) : w;
        const int r0 = a * 16;
        f32x4 o[4];
        float mrun[4], lrun[4];
#pragma unroll
        for (int i = 0; i < 4; ++i) {
            o[i] = (f32x4){0.f, 0.f, 0.f, 0.f};
            mrun[i] = -3.0e38f;
            lrun[i] = 0.f;
        }
        const int nch = (a >> 2) + 1;
        unsigned short* pw = Ps + w * 1152;

        for (int j = 0; j < nch; ++j) {
            // S = (q*scale*log2e) . k   over 64 keys (4 n-tiles), K-dim 64 (2 k-tiles)
            f32x4 s[4];
#pragma unroll
            for (int nt = 0; nt < 4; ++nt) s[nt] = (f32x4){0.f, 0.f, 0.f, 0.f};
#pragma unroll
            for (int kt = 0; kt < 2; ++kt) {
                short8 qf = *(const short8*)(Qs + (r0 + mr) * 72 + kt * 32 + g * 8);
#pragma unroll
                for (int nt = 0; nt < 4; ++nt) {
                    short8 kf = *(const short8*)(Ks + (j * 64 + nt * 16 + mr) * 72 + kt * 32 + g * 8);
                    s[nt] = __builtin_amdgcn_mfma_f32_16x16x32_bf16(qf, kf, s[nt], 0, 0, 0);
                }
            }
            // causal mask (only the diagonal chunk needs it; branch is wave-uniform)
            if (j * 64 + 63 > r0) {
#pragma unroll
                for (int nt = 0; nt < 4; ++nt) {
                    const int key = j * 64 + nt * 16 + mr;
#pragma unroll
                    for (int r = 0; r < 4; ++r) {
                        const int row = r0 + g * 4 + r;
                        if (key > row) s[nt][r] = -3.0e38f;
                    }
                }
            }
            // row max across 64 keys (4 regs + 16-lane shuffle tree)
            float cm[4];
#pragma unroll
            for (int r = 0; r < 4; ++r) {
                cm[r] = fmaxf(fmaxf(s[0][r], s[1][r]), fmaxf(s[2][r], s[3][r]));
                cm[r] = fmaxf(cm[r], __shfl_xor(cm[r], 1, 64));
                cm[r] = fmaxf(cm[r], __shfl_xor(cm[r], 2, 64));
                cm[r] = fmaxf(cm[r], __shfl_xor(cm[r], 4, 64));
                cm[r] = fmaxf(cm[r], __shfl_xor(cm[r], 8, 64));
            }
            float al[4];
#pragma unroll
            for (int r = 0; r < 4; ++r) {
                float mn = fmaxf(mrun[r], cm[r]);
                al[r] = exp2f(mrun[r] - mn);
                mrun[r] = mn;
            }
            // P = exp2(S - m), accumulate row sums, stash P in A-operand layout via LDS
            float rs[4] = {0.f, 0.f, 0.f, 0.f};
#pragma unroll
            for (int nt = 0; nt < 4; ++nt) {
#pragma unroll
                for (int r = 0; r < 4; ++r) {
                    float p = exp2f(s[nt][r] - mrun[r]);
                    rs[r] += p;
                    pw[(g * 4 + r) * 72 + nt * 16 + mr] = f2bf(p);
                }
            }
#pragma unroll
            for (int r = 0; r < 4; ++r) {
                rs[r] += __shfl_xor(rs[r], 1, 64);
                rs[r] += __shfl_xor(rs[r], 2, 64);
                rs[r] += __shfl_xor(rs[r], 4, 64);
                rs[r] += __shfl_xor(rs[r], 8, 64);
                lrun[r] = lrun[r] * al[r] + rs[r];
            }
            // O = O*alpha + P @ V
#pragma unroll
            for (int hn = 0; hn < 4; ++hn)
#pragma unroll
                for (int r = 0; r < 4; ++r) o[hn][r] *= al[r];
#pragma unroll
            for (int kt = 0; kt < 2; ++kt) {
                short8 pf = *(const short8*)(pw + mr * 72 + kt * 32 + g * 8);
#pragma unroll
                for (int hn = 0; hn < 4; ++hn) {
                    short8 vf = *(const short8*)(Vt + (hn * 16 + mr) * 264 + j * 64 + kt * 32 + g * 8);
                    o[hn] = __builtin_amdgcn_mfma_f32_16x16x32_bf16(pf, vf, o[hn], 0, 0, 0);
                }
            }
        }
        // normalize and store fp32 output
        float* ob = out + ((size_t)b * TT + r0) * HH;
#pragma unroll
        for (int r = 0; r < 4; ++r) {
            const float inv = 1.0f / lrun[r];
#pragma unroll
            for (int hn = 0; hn < 4; ++hn)
                ob[(g * 4 + r) * HH + hn * 16 + mr] = o[hn][r] * inv;
        }
    }
}

extern "C" void kernel_launch(void* const* d_in, const int* in_sizes, int n_in,
                              void* d_out, int out_size, void* d_ws, size_t ws_size,
                              hipStream_t stream) {
    const float* x  = (const float*)d_in[0];
    const float* Wq = (const float*)d_in[1];
    const float* Wk = (const float*)d_in[2];
    const float* Wv = (const float*)d_in[3];
    unsigned short* Wt = (unsigned short*)d_ws;   // 192*384 bf16 = 147456 B
    float* out = (float*)d_out;

    prep_kernel<<<288, 256, 0, stream>>>(Wq, Wk, Wv, Wt);
    attn_kernel<<<BB, 512, 0, stream>>>(x, Wt, out);
}

// Round 2
// 605.308 us; speedup vs baseline: 1.0806x; 1.0806x over previous
//
#include <hip/hip_runtime.h>

#define BB 1024
#define TT 256
#define EE 384
#define HH 64

typedef float  f32x4  __attribute__((ext_vector_type(4)));
typedef short  short8 __attribute__((ext_vector_type(8)));
typedef unsigned short us4 __attribute__((ext_vector_type(4)));

// fp32 -> bf16 round-to-nearest-even
__device__ __forceinline__ unsigned short f2bf(float f) {
    unsigned int u = __float_as_uint(f);
    u += 0x7FFFu + ((u >> 16) & 1u);
    return (unsigned short)(u >> 16);
}

__device__ __forceinline__ void gl_lds16(const void* g, void* l) {
    __builtin_amdgcn_global_load_lds(
        (const __attribute__((address_space(1))) unsigned int*)g,
        (__attribute__((address_space(3))) unsigned int*)l, 16, 0, 0);
}

// ============================ SPLIT PATH ============================

// Wt2: per-kt-sliced, XOR-swizzled LDS image of [Wq*scale | Wk | Wv]^T.
// Element (n, k = kt*32 + c*8 + e) stored at  kt*6144 + n*32 + (c^(n&3))*8 + e.
__global__ void prep2_kernel(const float* __restrict__ Wq, const float* __restrict__ Wk,
                             const float* __restrict__ Wv, unsigned short* __restrict__ Wt2) {
    int i = blockIdx.x * 256 + threadIdx.x;     // 12*6144 = 73728 = 288*256
    if (i >= 12 * 6144) return;
    int kt = i / 6144;
    int r1 = i - kt * 6144;
    int n  = r1 >> 5;
    int r2 = r1 & 31;
    int sc = r2 >> 3, e = r2 & 7;
    int c  = sc ^ (n & 3);
    int k  = kt * 32 + c * 8 + e;
    float v;
    if (n < 64)       v = Wq[k * HH + n] * 0.18033688011112042f;   // 0.125 * log2(e)
    else if (n < 128) v = Wk[k * HH + (n - 64)];
    else              v = Wv[k * HH + (n - 128)];
    Wt2[i] = f2bf(v);
}

// QKV projection. 256 thr / 4 waves; 128 rows per block; grid 2048.
// x + weight slices staged per k-step via global_load_lds (coalesced, source-side
// XOR swizzle -> conflict-free LDS fragment reads). ~190 regs -> 2 blocks/CU.
// Outputs (bf16): Qimg plain [b][t][h]; Kimg [b][t][hchunk^ (t&7)]; Vimg [b][h][tchunk^(h&7)].
__global__ __launch_bounds__(256, 2) void qkv_kernel(const float* __restrict__ x,
                                                     const unsigned short* __restrict__ Wt2,
                                                     unsigned short* __restrict__ Qimg,
                                                     unsigned short* __restrict__ Kimg,
                                                     unsigned short* __restrict__ Vimg) {
    __shared__ __align__(16) float          xs[128 * 32];   // 16 KB, row = 8 swizzled 16B chunks
    __shared__ __align__(16) unsigned short wts[6144];      // 12 KB, row = 4 swizzled 16B chunks

    const int tid  = threadIdx.x;
    const int lane = tid & 63;
    const int w    = tid >> 6;          // wave 0..3
    const int g    = lane >> 4;
    const int mr   = lane & 15;
    const int m7   = mr & 7;
    const int m3   = mr & 3;
    const long rows0 = (long)blockIdx.x * 128;

    f32x4 acc[2][12];
#pragma unroll
    for (int ti = 0; ti < 2; ++ti)
#pragma unroll
        for (int nt = 0; nt < 12; ++nt) acc[ti][nt] = (f32x4){0.f, 0.f, 0.f, 0.f};

    const int swb = (g ^ m3) << 3;      // B-frag swizzled chunk offset (halfwords)

    for (int kt = 0; kt < 12; ++kt) {
        __syncthreads();
        // stage x slice: 128 rows x 32 floats, 16B chunks permuted by c^(r&7) on the SOURCE side
#pragma unroll
        for (int j = 0; j < 4; ++j) {
            int chunk = j * 256 + tid;
            int r = chunk >> 3, c = chunk & 7;
            const float* src = x + (rows0 + r) * EE + kt * 32 + ((c ^ (r & 7)) << 2);
            gl_lds16(src, xs + (j * 256 + w * 64) * 4);
        }
        // stage weight slice (already swizzled in global) : 12 KB contiguous
#pragma unroll
        for (int j = 0; j < 3; ++j) {
            int ch = j * 256 + tid;
            gl_lds16(Wt2 + kt * 6144 + ch * 8, wts + (j * 256 + w * 64) * 8);
        }
        __syncthreads();

        short8 afr[2];
#pragma unroll
        for (int ti = 0; ti < 2; ++ti) {
            const int lr = w * 32 + ti * 16 + mr;
            const float* base = xs + lr * 32;
            f32x4 lo = *(const f32x4*)(base + (((2 * g)     ^ m7) << 2));
            f32x4 hi = *(const f32x4*)(base + (((2 * g + 1) ^ m7) << 2));
            union { short8 v; unsigned short u[8]; } cv;
            cv.u[0] = f2bf(lo.x); cv.u[1] = f2bf(lo.y); cv.u[2] = f2bf(lo.z); cv.u[3] = f2bf(lo.w);
            cv.u[4] = f2bf(hi.x); cv.u[5] = f2bf(hi.y); cv.u[6] = f2bf(hi.z); cv.u[7] = f2bf(hi.w);
            afr[ti] = cv.v;
        }
#pragma unroll
        for (int nt = 0; nt < 12; ++nt) {
            short8 bfr = *(const short8*)(wts + (nt * 16 + mr) * 32 + swb);
            acc[0][nt] = __builtin_amdgcn_mfma_f32_16x16x32_bf16(afr[0], bfr, acc[0][nt], 0, 0, 0);
            acc[1][nt] = __builtin_amdgcn_mfma_f32_16x16x32_bf16(afr[1], bfr, acc[1][nt], 0, 0, 0);
        }
    }

    // epilogue -> bf16 images
    const int b  = blockIdx.x >> 1;
    const int t0 = (blockIdx.x & 1) * 128;
    unsigned short* Qb = Qimg + (size_t)b * 16384;
    unsigned short* Kb = Kimg + (size_t)b * 16384;
    unsigned short* Vb = Vimg + (size_t)b * 16384;

#pragma unroll
    for (int ti = 0; ti < 2; ++ti) {
        const int tbase = t0 + w * 32 + ti * 16;
#pragma unroll
        for (int nt = 0; nt < 12; ++nt) {
            f32x4 v = acc[ti][nt];
            if (nt < 4) {
                const int h = nt * 16 + mr;
#pragma unroll
                for (int r = 0; r < 4; ++r)
                    Qb[(tbase + g * 4 + r) * 64 + h] = f2bf(v[r]);
            } else if (nt < 8) {
                const int hc = (nt - 4) * 2 + (mr >> 3);
#pragma unroll
                for (int r = 0; r < 4; ++r) {
                    const int t = tbase + g * 4 + r;
                    Kb[t * 64 + ((hc ^ (t & 7)) << 3) + m7] = f2bf(v[r]);
                }
            } else {
                const int h  = (nt - 8) * 16 + mr;
                const int tq = tbase + g * 4;
                const int sw = (tq >> 3) ^ m7;
                us4 pk;
                pk.x = f2bf(v[0]); pk.y = f2bf(v[1]); pk.z = f2bf(v[2]); pk.w = f2bf(v[3]);
                *(us4*)(Vb + h * 256 + sw * 8 + (tq & 7)) = pk;
            }
        }
    }
}

// Flash attention. 512 thr / 8 waves, one block per batch, grid 1024.
// LDS = 80 KB exactly (swizzled, pad-free) and <=128 regs -> 2 blocks/CU.
__global__ __launch_bounds__(512, 4) void attn2_kernel(const unsigned short* __restrict__ Qimg,
                                                       const unsigned short* __restrict__ Kimg,
                                                       const unsigned short* __restrict__ Vimg,
                                                       float* __restrict__ out) {
    __shared__ __align__(16) unsigned short Ks[16384];   // 32 KB  K[t][chunk^(t&7)]
    __shared__ __align__(16) unsigned short Vs[16384];   // 32 KB  V^T[h][chunk^(h&7)]
    __shared__ __align__(16) unsigned short Ps[8192];    // 16 KB  per-wave P 16x64 swizzled

    const int tid  = threadIdx.x;
    const int lane = tid & 63;
    const int w    = tid >> 6;          // wave 0..7
    const int g    = lane >> 4;
    const int mr   = lane & 15;
    const int m7   = mr & 7;
    const int b    = blockIdx.x;

    const unsigned short* Qb = Qimg + (size_t)b * 16384;
    const unsigned short* Kb = Kimg + (size_t)b * 16384;
    const unsigned short* Vb = Vimg + (size_t)b * 16384;

    // Q fragments straight from global (4 scattered 16B loads; overlap with staging)
    short8 qfr[2][2];
#pragma unroll
    for (int p = 0; p < 2; ++p) {
        const int t0 = (w + p * 8) * 16;
#pragma unroll
        for (int kt = 0; kt < 2; ++kt)
            qfr[p][kt] = *(const short8*)(Qb + (t0 + mr) * 64 + kt * 32 + g * 8);
    }

    // stage K,V (contiguous LDS images -> perfectly coalesced)
#pragma unroll
    for (int j = 0; j < 4; ++j) {
        int ch = j * 512 + tid;
        gl_lds16(Kb + ch * 8, Ks + (j * 512 + w * 64) * 8);
    }
#pragma unroll
    for (int j = 0; j < 4; ++j) {
        int ch = j * 512 + tid;
        gl_lds16(Vb + ch * 8, Vs + (j * 512 + w * 64) * 8);
    }
    __syncthreads();

    const int swv0 = ((0 * 4 + g) ^ m7) << 3;   // swizzled chunk offsets (halfwords)
    const int swv1 = ((1 * 4 + g) ^ m7) << 3;
    unsigned short* pw = Ps + w * 1024;

    short8 ones;
#pragma unroll
    for (int i = 0; i < 8; ++i) ones[i] = (short)0x3F80;   // bf16 1.0

#pragma unroll
    for (int p = 0; p < 2; ++p) {
        const int a   = w + p * 8;
        const int r0  = a * 16;
        const int nch = (a >> 2) + 1;

        f32x4 o[4];
        f32x4 ls = (f32x4){0.f, 0.f, 0.f, 0.f};
        float mrun[4];
#pragma unroll
        for (int i = 0; i < 4; ++i) { o[i] = (f32x4){0.f, 0.f, 0.f, 0.f}; mrun[i] = -3.0e38f; }

        for (int j = 0; j < nch; ++j) {
            // S = Q K^T   (scale*log2e folded into Q)
            f32x4 s[4];
#pragma unroll
            for (int nt = 0; nt < 4; ++nt) s[nt] = (f32x4){0.f, 0.f, 0.f, 0.f};
#pragma unroll
            for (int kt = 0; kt < 2; ++kt) {
                const short8 qf = qfr[p][kt];
                const int swv = kt ? swv1 : swv0;
#pragma unroll
                for (int nt = 0; nt < 4; ++nt) {
                    short8 kf = *(const short8*)(Ks + (j * 64 + nt * 16 + mr) * 64 + swv);
                    s[nt] = __builtin_amdgcn_mfma_f32_16x16x32_bf16(qf, kf, s[nt], 0, 0, 0);
                }
            }
            // causal mask: only the last chunk contains the diagonal
            if (j == nch - 1) {
#pragma unroll
                for (int nt = 0; nt < 4; ++nt) {
                    const int key = j * 64 + nt * 16 + mr;
#pragma unroll
                    for (int r = 0; r < 4; ++r)
                        if (key > r0 + g * 4 + r) s[nt][r] = -3.0e38f;
                }
            }
            // row max (4 regs + 16-lane shuffle tree)
            float cm[4], al[4];
#pragma unroll
            for (int r = 0; r < 4; ++r) {
                cm[r] = fmaxf(fmaxf(s[0][r], s[1][r]), fmaxf(s[2][r], s[3][r]));
                cm[r] = fmaxf(cm[r], __shfl_xor(cm[r], 1, 64));
                cm[r] = fmaxf(cm[r], __shfl_xor(cm[r], 2, 64));
                cm[r] = fmaxf(cm[r], __shfl_xor(cm[r], 4, 64));
                cm[r] = fmaxf(cm[r], __shfl_xor(cm[r], 8, 64));
                float mn = fmaxf(mrun[r], cm[r]);
                al[r] = exp2f(mrun[r] - mn);
                mrun[r] = mn;
            }
            // P = exp2(S - m) -> bf16 -> swizzled per-wave scratch (C-layout writes)
#pragma unroll
            for (int nt = 0; nt < 4; ++nt) {
#pragma unroll
                for (int r = 0; r < 4; ++r) {
                    const int lr = g * 4 + r;
                    const int sw = (nt * 2 + (mr >> 3)) ^ (lr & 7);
                    pw[lr * 64 + (sw << 3) + m7] = f2bf(exp2f(s[nt][r] - mrun[r]));
                }
            }
            // rescale, then O += P V and l += P*1 (ones-column MFMA replaces shuffle sums)
#pragma unroll
            for (int hn = 0; hn < 4; ++hn)
#pragma unroll
                for (int r = 0; r < 4; ++r) o[hn][r] *= al[r];
#pragma unroll
            for (int r = 0; r < 4; ++r) ls[r] *= al[r];
#pragma unroll
            for (int kt = 0; kt < 2; ++kt) {
                const int swv = kt ? swv1 : swv0;
                short8 pf = *(const short8*)(pw + mr * 64 + swv);
#pragma unroll
                for (int hn = 0; hn < 4; ++hn) {
                    short8 vf = *(const short8*)(Vs + (hn * 16 + mr) * 256 + j * 64 + swv);
                    o[hn] = __builtin_amdgcn_mfma_f32_16x16x32_bf16(pf, vf, o[hn], 0, 0, 0);
                }
                ls = __builtin_amdgcn_mfma_f32_16x16x32_bf16(pf, ones, ls, 0, 0, 0);
            }
        }
        // normalize + store
        float* ob = out + ((size_t)b * TT + r0) * HH;
#pragma unroll
        for (int r = 0; r < 4; ++r) {
            const float inv = 1.0f / ls[r];
#pragma unroll
            for (int hn = 0; hn < 4; ++hn)
                ob[(g * 4 + r) * HH + hn * 16 + mr] = o[hn][r] * inv;
        }
    }
}

// ============================ FALLBACK PATH (R1, proven) ============================

__global__ void prep_kernel(const float* __restrict__ Wq, const float* __restrict__ Wk,
                            const float* __restrict__ Wv, unsigned short* __restrict__ Wt) {
    int i = blockIdx.x * 256 + threadIdx.x;
    if (i >= 192 * EE) return;
    int n = i / EE, k = i - n * EE;
    float v;
    if (n < 64)       v = Wq[k * HH + n] * 0.18033688011112042f;
    else if (n < 128) v = Wk[k * HH + (n - 64)];
    else              v = Wv[k * HH + (n - 128)];
    Wt[i] = f2bf(v);
}

__global__ __launch_bounds__(512, 2) void attn_kernel(const float* __restrict__ x,
                                                      const unsigned short* __restrict__ Wt,
                                                      float* __restrict__ out) {
    __shared__ unsigned short Qs[TT * 72];
    __shared__ unsigned short Ksh[TT * 72];
    __shared__ unsigned short Vt[HH * 264];
    __shared__ unsigned short Psc[8 * 1152];

    const int tid  = threadIdx.x;
    const int lane = tid & 63;
    const int w    = tid >> 6;
    const int g    = lane >> 4;
    const int mr   = lane & 15;
    const int b    = blockIdx.x;
    const float* xb = x + (size_t)b * (TT * EE);

    f32x4 acc[2][12];
#pragma unroll
    for (int ti = 0; ti < 2; ++ti)
#pragma unroll
        for (int nt = 0; nt < 12; ++nt) acc[ti][nt] = (f32x4){0.f, 0.f, 0.f, 0.f};

    const int M0a = (2 * w) * 16, M0b = (2 * w + 1) * 16;

    for (int kt = 0; kt < 12; ++kt) {
        const int k0 = kt * 32 + g * 8;
        short8 bfr[12];
#pragma unroll
        for (int nt = 0; nt < 12; ++nt)
            bfr[nt] = *(const short8*)(Wt + (size_t)(nt * 16 + mr) * EE + k0);
        short8 afr[2];
#pragma unroll
        for (int ti = 0; ti < 2; ++ti) {
            const int m0 = ti ? M0b : M0a;
            const float* ap = xb + (size_t)(m0 + mr) * EE + k0;
            f32x4 lo = *(const f32x4*)ap;
            f32x4 hi = *(const f32x4*)(ap + 4);
            union { short8 v; unsigned short u[8]; } cv;
            cv.u[0] = f2bf(lo.x); cv.u[1] = f2bf(lo.y); cv.u[2] = f2bf(lo.z); cv.u[3] = f2bf(lo.w);
            cv.u[4] = f2bf(hi.x); cv.u[5] = f2bf(hi.y); cv.u[6] = f2bf(hi.z); cv.u[7] = f2bf(hi.w);
            afr[ti] = cv.v;
        }
#pragma unroll
        for (int nt = 0; nt < 12; ++nt) {
            acc[0][nt] = __builtin_amdgcn_mfma_f32_16x16x32_bf16(afr[0], bfr[nt], acc[0][nt], 0, 0, 0);
            acc[1][nt] = __builtin_amdgcn_mfma_f32_16x16x32_bf16(afr[1], bfr[nt], acc[1][nt], 0, 0, 0);
        }
    }

#pragma unroll
    for (int ti = 0; ti < 2; ++ti) {
        const int row = (ti ? M0b : M0a) + g * 4;
#pragma unroll
        for (int nt = 0; nt < 12; ++nt) {
            f32x4 v = acc[ti][nt];
            if (nt < 4) {
                const int col = nt * 16 + mr;
#pragma unroll
                for (int r = 0; r < 4; ++r) Qs[(row + r) * 72 + col] = f2bf(v[r]);
            } else if (nt < 8) {
                const int col = (nt - 4) * 16 + mr;
#pragma unroll
                for (int r = 0; r < 4; ++r) Ksh[(row + r) * 72 + col] = f2bf(v[r]);
            } else {
                const int h = (nt - 8) * 16 + mr;
                us4 pk;
                pk.x = f2bf(v[0]); pk.y = f2bf(v[1]); pk.z = f2bf(v[2]); pk.w = f2bf(v[3]);
                *(us4*)(&Vt[h * 264 + row]) = pk;
            }
        }
    }
    __syncthreads();

#pragma unroll
    for (int pass = 0; pass < 2; ++pass) {
        const int a  = pass ? (15 - w) : w;
        const int r0 = a * 16;
        f32x4 o[4];
        float mrun[4], lrun[4];
#pragma unroll
        for (int i = 0; i < 4; ++i) {
            o[i] = (f32x4){0.f, 0.f, 0.f, 0.f};
            mrun[i] = -3.0e38f; lrun[i] = 0.f;
        }
        const int nch = (a >> 2) + 1;
        unsigned short* pwv = Psc + w * 1152;

        for (int j = 0; j < nch; ++j) {
            f32x4 s[4];
#pragma unroll
            for (int nt = 0; nt < 4; ++nt) s[nt] = (f32x4){0.f, 0.f, 0.f, 0.f};
#pragma unroll
            for (int kt = 0; kt < 2; ++kt) {
                short8 qf = *(const short8*)(Qs + (r0 + mr) * 72 + kt * 32 + g * 8);
#pragma unroll
                for (int nt = 0; nt < 4; ++nt) {
                    short8 kf = *(const short8*)(Ksh + (j * 64 + nt * 16 + mr) * 72 + kt * 32 + g * 8);
                    s[nt] = __builtin_amdgcn_mfma_f32_16x16x32_bf16(qf, kf, s[nt], 0, 0, 0);
                }
            }
            if (j * 64 + 63 > r0) {
#pragma unroll
                for (int nt = 0; nt < 4; ++nt) {
                    const int key = j * 64 + nt * 16 + mr;
#pragma unroll
                    for (int r = 0; r < 4; ++r)
                        if (key > r0 + g * 4 + r) s[nt][r] = -3.0e38f;
                }
            }
            float cm[4];
#pragma unroll
            for (int r = 0; r < 4; ++r) {
                cm[r] = fmaxf(fmaxf(s[0][r], s[1][r]), fmaxf(s[2][r], s[3][r]));
                cm[r] = fmaxf(cm[r], __shfl_xor(cm[r], 1, 64));
                cm[r] = fmaxf(cm[r], __shfl_xor(cm[r], 2, 64));
                cm[r] = fmaxf(cm[r], __shfl_xor(cm[r], 4, 64));
                cm[r] = fmaxf(cm[r], __shfl_xor(cm[r], 8, 64));
            }
            float al[4];
#pragma unroll
            for (int r = 0; r < 4; ++r) {
                float mn = fmaxf(mrun[r], cm[r]);
                al[r] = exp2f(mrun[r] - mn);
                mrun[r] = mn;
            }
            float rs[4] = {0.f, 0.f, 0.f, 0.f};
#pragma unroll
            for (int nt = 0; nt < 4; ++nt) {
#pragma unroll
                for (int r = 0; r < 4; ++r) {
                    float pv = exp2f(s[nt][r] - mrun[r]);
                    rs[r] += pv;
                    pwv[(g * 4 + r) * 72 + nt * 16 + mr] = f2bf(pv);
                }
            }
#pragma unroll
            for (int r = 0; r < 4; ++r) {
                rs[r] += __shfl_xor(rs[r], 1, 64);
                rs[r] += __shfl_xor(rs[r], 2, 64);
                rs[r] += __shfl_xor(rs[r], 4, 64);
                rs[r] += __shfl_xor(rs[r], 8, 64);
                lrun[r] = lrun[r] * al[r] + rs[r];
            }
#pragma unroll
            for (int hn = 0; hn < 4; ++hn)
#pragma unroll
                for (int r = 0; r < 4; ++r) o[hn][r] *= al[r];
#pragma unroll
            for (int kt = 0; kt < 2; ++kt) {
                short8 pf = *(const short8*)(pwv + mr * 72 + kt * 32 + g * 8);
#pragma unroll
                for (int hn = 0; hn < 4; ++hn) {
                    short8 vf = *(const short8*)(Vt + (hn * 16 + mr) * 264 + j * 64 + kt * 32 + g * 8);
                    o[hn] = __builtin_amdgcn_mfma_f32_16x16x32_bf16(pf, vf, o[hn], 0, 0, 0);
                }
            }
        }
        float* ob = out + ((size_t)b * TT + r0) * HH;
#pragma unroll
        for (int r = 0; r < 4; ++r) {
            const float inv = 1.0f / lrun[r];
#pragma unroll
            for (int hn = 0; hn < 4; ++hn)
                ob[(g * 4 + r) * HH + hn * 16 + mr] = o[hn][r] * inv;
        }
    }
}

// ============================ launcher ============================

extern "C" void kernel_launch(void* const* d_in, const int* in_sizes, int n_in,
                              void* d_out, int out_size, void* d_ws, size_t ws_size,
                              hipStream_t stream) {
    const float* x  = (const float*)d_in[0];
    const float* Wq = (const float*)d_in[1];
    const float* Wk = (const float*)d_in[2];
    const float* Wv = (const float*)d_in[3];
    float* out = (float*)d_out;

    const size_t img = (size_t)1024 * 16384;            // elements per image (bf16)
    const size_t need = 147456 + 3 * img * 2;           // Wt2 + Q,K,V images  (~96.2 MB)

    if (ws_size >= need) {
        unsigned short* Wt2  = (unsigned short*)d_ws;
        unsigned short* Qimg = (unsigned short*)((char*)d_ws + 147456);
        unsigned short* Kimg = Qimg + img;
        unsigned short* Vimg = Kimg + img;
        prep2_kernel<<<288, 256, 0, stream>>>(Wq, Wk, Wv, Wt2);
        qkv_kernel<<<2048, 256, 0, stream>>>(x, Wt2, Qimg, Kimg, Vimg);
        attn2_kernel<<<1024, 512, 0, stream>>>(Qimg, Kimg, Vimg, out);
    } else {
        unsigned short* Wt = (unsigned short*)d_ws;     // 147456 B (fits: R1 ran with this)
        prep_kernel<<<288, 256, 0, stream>>>(Wq, Wk, Wv, Wt);
        attn_kernel<<<BB, 512, 0, stream>>>(x, Wt, out);
    }
}